// Round 12
// baseline (1315.314 us; speedup 1.0000x reference)
//
#include <hip/hip_runtime.h>
#include <hip/hip_cooperative_groups.h>
#include <math.h>

namespace cg = cooperative_groups;

#define NN 4096
#define NE 131072
#define NCLS 41476
#define NPAD 41600  // 325 * 128

typedef __attribute__((ext_vector_type(8))) unsigned short ushort8;
typedef __attribute__((ext_vector_type(8))) __bf16 bf16x8;
typedef __attribute__((ext_vector_type(4))) float f32x4;

__device__ __forceinline__ unsigned short f2bf(float f) {
  unsigned u = __float_as_uint(f);
  unsigned r = u + 0x7fffu + ((u >> 16) & 1u);  // RNE
  return (unsigned short)(r >> 16);
}
__device__ __forceinline__ float bf2f(unsigned short u) {
  return __uint_as_float(((unsigned)u) << 16);
}

// ---------------- shared-memory union for the trunk mega-kernel ----------------
struct SMemG {
  unsigned short As[32 * 64];
  unsigned short Bs[128 * 64];
  float sc[256], sh[256];
  float sas[4][32], sad[4][32];
};
struct SMemA {
  int sld[128];
  float wld[128];
  float red[3][256];
  float eld[128];
  float sden[4];
  float smax[256];
};
struct SMemB { float sc[128], sh[128]; };
union SMemU { SMemG g; SMemA a; SMemB bn; };

// ---------------- fused: weight transposes + edge degree count + embedding gather ----------------
struct CvtDesc { const float* src; unsigned short* dst; int K, N, ld, koff, tile0, ntx; };
struct CvtArgs { CvtDesc d[11]; };

__global__ void k_fused0(CvtArgs a, int cvtBlocks, const int* __restrict__ ei,
                         int* __restrict__ deg0, int* __restrict__ deg1,
                         const int* __restrict__ node_x, const float* __restrict__ uw,
                         const float* __restrict__ iw, unsigned short* __restrict__ x0) {
  int b = blockIdx.x;
  int tid = threadIdx.x;
  if (b < cvtBlocks) {
    __shared__ float s[32][33];
    int di = 0;
#pragma unroll
    for (int i = 1; i < 11; i++)
      if (a.d[i].tile0 <= b) di = i;
    const CvtDesc dd = a.d[di];
    int t = b - dd.tile0;
    int n0 = (t % dd.ntx) * 32, k0 = (t / dd.ntx) * 32;
    int c = tid & 31, r8 = tid >> 5;
#pragma unroll
    for (int r = 0; r < 4; r++) {
      int k = k0 + r8 + r * 8, n = n0 + c;
      s[r8 + r * 8][c] = (n < dd.N) ? dd.src[(size_t)k * dd.N + n] : 0.f;
    }
    __syncthreads();
#pragma unroll
    for (int r = 0; r < 4; r++) {
      int n = n0 + r8 + r * 8, k = k0 + c;
      dd.dst[(size_t)n * dd.ld + dd.koff + k] = f2bf(s[c][r8 + r * 8]);
    }
  } else if (b < cvtBlocks + 512) {
    int bid = b - cvtBlocks;
    for (int i = bid * 256 + tid; i < 2 * NE; i += 512 * 256) {
      int v = ei[i];
      atomicAdd((i < NE ? deg0 : deg1) + v, 1);
    }
  } else {
    int nb = b - cvtBlocks - 512;     // 2048 blocks, 2 nodes each
    int n = nb * 2 + (tid >> 7);
    int t = tid & 127;
    int u = node_x[n * 2], it = node_x[n * 2 + 1];
    float v = (t < 64) ? uw[u * 64 + t] : iw[it * 64 + (t - 64)];
    x0[n * 128 + t] = f2bf(v);
  }
}

// ---------------- bf16 MFMA GEMM, 128x128 tile (MLP layers) ----------------
template <int OUTBF>
__global__ __launch_bounds__(256) void k_bgemm(const unsigned short* __restrict__ A,
                                               const unsigned short* __restrict__ Bt,
                                               const float* __restrict__ bias,
                                               void* __restrict__ Cv, int N, int K, int relu) {
  __shared__ unsigned short As[128 * 128];
  __shared__ unsigned short Bs[128 * 128];
  int m0 = blockIdx.y * 128;
  int n0 = blockIdx.x * 128;
  int tid = threadIdx.x;
  int wave = tid >> 6, lane = tid & 63;
  int wm = (wave >> 1) * 64, wn = (wave & 1) * 64;
  int lr = lane & 15, lg = lane >> 4;
  f32x4 acc[4][4] = {};
  for (int k0 = 0; k0 < K; k0 += 128) {
#pragma unroll
    for (int i = 0; i < 8; i++) {
      int idx = tid + i * 256;
      int row = idx >> 4, ku = idx & 15;
      int sw = (ku ^ (row & 7)) * 8;
      *reinterpret_cast<ushort8*>(As + row * 128 + sw) =
          *reinterpret_cast<const ushort8*>(A + (size_t)(m0 + row) * K + k0 + ku * 8);
      *reinterpret_cast<ushort8*>(Bs + row * 128 + sw) =
          *reinterpret_cast<const ushort8*>(Bt + (size_t)(n0 + row) * K + k0 + ku * 8);
    }
    __syncthreads();
#pragma unroll
    for (int kk = 0; kk < 4; kk++) {
      bf16x8 af[4], bfr[4];
#pragma unroll
      for (int mi = 0; mi < 4; mi++) {
        int row = wm + mi * 16 + lr;
        af[mi] = __builtin_bit_cast(
            bf16x8, *reinterpret_cast<const ushort8*>(As + row * 128 + (((kk * 4 + lg) ^ (row & 7)) * 8)));
        int col = wn + mi * 16 + lr;
        bfr[mi] = __builtin_bit_cast(
            bf16x8, *reinterpret_cast<const ushort8*>(Bs + col * 128 + (((kk * 4 + lg) ^ (col & 7)) * 8)));
      }
#pragma unroll
      for (int mi = 0; mi < 4; mi++)
#pragma unroll
        for (int ni = 0; ni < 4; ni++)
          acc[mi][ni] = __builtin_amdgcn_mfma_f32_16x16x32_bf16(af[mi], bfr[ni], acc[mi][ni], 0, 0, 0);
    }
    __syncthreads();
  }
#pragma unroll
  for (int mi = 0; mi < 4; mi++) {
#pragma unroll
    for (int ni = 0; ni < 4; ni++) {
      int col = n0 + wn + ni * 16 + lr;
      if (col < N) {
        float bv = bias ? bias[col] : 0.f;
#pragma unroll
        for (int r = 0; r < 4; r++) {
          int row = m0 + wm + mi * 16 + lg * 4 + r;
          float v = acc[mi][ni][r] + bv;
          if (relu) v = fmaxf(v, 0.f);
          if (OUTBF)
            ((unsigned short*)Cv)[(size_t)row * N + col] = f2bf(v);
          else
            ((float*)Cv)[(size_t)row * N + col] = v;
        }
      }
    }
  }
}

// ---------------- pred GEMM (r8 form): B staged once, 8 M-tiles per block ----------------
__global__ __launch_bounds__(256) void k_pred_gemm(const unsigned short* __restrict__ A,
                                                   const unsigned short* __restrict__ Bt,
                                                   const float* __restrict__ bias,
                                                   float* __restrict__ C) {
  __shared__ unsigned short As[128 * 128];
  __shared__ unsigned short Bs[128 * 128];
  int n0 = blockIdx.x * 128;
  int tid = threadIdx.x;
  int wave = tid >> 6, lane = tid & 63;
  int wm = (wave >> 1) * 64, wn = (wave & 1) * 64;
  int lr = lane & 15, lg = lane >> 4;
#pragma unroll
  for (int i = 0; i < 8; i++) {
    int idx = tid + i * 256;
    int row = idx >> 4, ku = idx & 15;
    int sw = (ku ^ (row & 7)) * 8;
    *reinterpret_cast<ushort8*>(Bs + row * 128 + sw) =
        *reinterpret_cast<const ushort8*>(Bt + (size_t)(n0 + row) * 128 + ku * 8);
  }
  float bv[4];
  int colv[4];
#pragma unroll
  for (int ni = 0; ni < 4; ni++) {
    colv[ni] = n0 + wn + ni * 16 + lr;
    bv[ni] = (colv[ni] < NCLS) ? bias[colv[ni]] : 0.f;
  }
  int mt0 = blockIdx.y * 8;
  for (int mt = mt0; mt < mt0 + 8; ++mt) {
    int m0 = mt * 128;
    __syncthreads();  // Bs staged (first iter) / prev-iter As consumers done
#pragma unroll
    for (int i = 0; i < 8; i++) {
      int idx = tid + i * 256;
      int row = idx >> 4, ku = idx & 15;
      int sw = (ku ^ (row & 7)) * 8;
      *reinterpret_cast<ushort8*>(As + row * 128 + sw) =
          *reinterpret_cast<const ushort8*>(A + (size_t)(m0 + row) * 128 + ku * 8);
    }
    __syncthreads();
    f32x4 acc[4][4] = {};
#pragma unroll
    for (int kk = 0; kk < 4; kk++) {
      bf16x8 af[4], bfr[4];
#pragma unroll
      for (int mi = 0; mi < 4; mi++) {
        int row = wm + mi * 16 + lr;
        af[mi] = __builtin_bit_cast(
            bf16x8, *reinterpret_cast<const ushort8*>(As + row * 128 + (((kk * 4 + lg) ^ (row & 7)) * 8)));
        int col = wn + mi * 16 + lr;
        bfr[mi] = __builtin_bit_cast(
            bf16x8, *reinterpret_cast<const ushort8*>(Bs + col * 128 + (((kk * 4 + lg) ^ (col & 7)) * 8)));
      }
#pragma unroll
      for (int mi = 0; mi < 4; mi++)
#pragma unroll
        for (int ni = 0; ni < 4; ni++)
          acc[mi][ni] = __builtin_amdgcn_mfma_f32_16x16x32_bf16(af[mi], bfr[ni], acc[mi][ni], 0, 0, 0);
    }
#pragma unroll
    for (int mi = 0; mi < 4; mi++) {
#pragma unroll
      for (int ni = 0; ni < 4; ni++) {
        if (colv[ni] < NCLS) {
#pragma unroll
          for (int r = 0; r < 4; r++) {
            int row = m0 + wm + mi * 16 + lg * 4 + r;
            C[(size_t)row * NCLS + colv[ni]] = acc[mi][ni][r] + bv[ni];
          }
        }
      }
    }
  }
}

// ---------------- device bodies for the trunk mega-kernel ----------------
// 32x128 GEMM tile; MODE 0=plain 1=bnfinal+affine-fp32-A 2=dots-epilogue
template <int MODE>
__device__ void d_bgemm_s(SMemU& sm, int bx, int by, const void* Av,
                          const unsigned short* Bt, const float* bias,
                          unsigned short* C, int ldC, int K, int relu,
                          const float* psum, const float* psq,
                          const float* bng, const float* bnb,
                          const float* asrc, const float* adst,
                          float* o_as, float* o_ad) {
  __syncthreads();
  int m0 = by * 32;
  int n0 = bx * 128;
  int tid = threadIdx.x;
  int wave = tid >> 6, lane = tid & 63;
  int wn = wave * 32;
  int lr = lane & 15, lg = lane >> 4;
  if (MODE == 1) {
    if (tid < K) {
      int S = 16384 / K;
      float s = 0.f, s2 = 0.f;
      for (int i = 0; i < S; i++) {
        s += psum[(size_t)i * K + tid];
        s2 += psq[(size_t)i * K + tid];
      }
      float invM = 1.f / (float)NN;
      float mu = s * invM;
      float var = s2 * invM - mu * mu;
      float scv = bng[tid] * rsqrtf(var + 1e-5f);
      sm.g.sc[tid] = scv;
      sm.g.sh[tid] = bnb[tid] - mu * scv;
    }
    __syncthreads();
  }
  f32x4 acc[2][2] = {};
  for (int k0 = 0; k0 < K; k0 += 64) {
    {
      int row = tid >> 3, uu = tid & 7, sw = (uu ^ (row & 7)) * 8;
      if (MODE == 1) {
        const float* Af = (const float*)Av;
        const float* p = Af + (size_t)(m0 + row) * K + k0 + uu * 8;
        float4 p0 = *reinterpret_cast<const float4*>(p);
        float4 p1 = *reinterpret_cast<const float4*>(p + 4);
        int kb = k0 + uu * 8;
        float pv[8] = {p0.x, p0.y, p0.z, p0.w, p1.x, p1.y, p1.z, p1.w};
        ushort8 o;
#pragma unroll
        for (int j = 0; j < 8; j++)
          o[j] = f2bf(fmaxf(pv[j] * sm.g.sc[kb + j] + sm.g.sh[kb + j], 0.f));
        *reinterpret_cast<ushort8*>(sm.g.As + row * 64 + sw) = o;
      } else {
        *reinterpret_cast<ushort8*>(sm.g.As + row * 64 + sw) =
            *reinterpret_cast<const ushort8*>((const unsigned short*)Av + (size_t)(m0 + row) * K + k0 + uu * 8);
      }
    }
#pragma unroll
    for (int i = 0; i < 4; i++) {
      int idx = tid + i * 256;
      int row = idx >> 3, uu = idx & 7, sw = (uu ^ (row & 7)) * 8;
      *reinterpret_cast<ushort8*>(sm.g.Bs + row * 64 + sw) =
          *reinterpret_cast<const ushort8*>(Bt + (size_t)(n0 + row) * K + k0 + uu * 8);
    }
    __syncthreads();
#pragma unroll
    for (int kk = 0; kk < 2; kk++) {
      bf16x8 af[2], bfr[2];
#pragma unroll
      for (int mi = 0; mi < 2; mi++) {
        int row = mi * 16 + lr;
        af[mi] = __builtin_bit_cast(
            bf16x8, *reinterpret_cast<const ushort8*>(sm.g.As + row * 64 + (((kk * 4 + lg) ^ (row & 7)) * 8)));
        int col = wn + mi * 16 + lr;
        bfr[mi] = __builtin_bit_cast(
            bf16x8, *reinterpret_cast<const ushort8*>(sm.g.Bs + col * 64 + (((kk * 4 + lg) ^ (col & 7)) * 8)));
      }
#pragma unroll
      for (int mi = 0; mi < 2; mi++)
#pragma unroll
        for (int ni = 0; ni < 2; ni++)
          acc[mi][ni] = __builtin_amdgcn_mfma_f32_16x16x32_bf16(af[mi], bfr[ni], acc[mi][ni], 0, 0, 0);
    }
    __syncthreads();
  }
  float dss[2][4] = {}, dsd[2][4] = {};
#pragma unroll
  for (int mi = 0; mi < 2; mi++) {
#pragma unroll
    for (int ni = 0; ni < 2; ni++) {
      int col = n0 + wn + ni * 16 + lr;
      float bv = bias ? bias[col] : 0.f;
      float ac = (MODE == 2) ? asrc[col] : 0.f;
      float dc = (MODE == 2) ? adst[col] : 0.f;
#pragma unroll
      for (int r = 0; r < 4; r++) {
        int row = m0 + mi * 16 + lg * 4 + r;
        float v = acc[mi][ni][r] + bv;
        if (relu) v = fmaxf(v, 0.f);
        C[(size_t)row * ldC + col] = f2bf(v);
        if (MODE == 2) { dss[mi][r] += v * ac; dsd[mi][r] += v * dc; }
      }
    }
  }
  if (MODE == 2) {
#pragma unroll
    for (int mi = 0; mi < 2; mi++)
#pragma unroll
      for (int r = 0; r < 4; r++) {
#pragma unroll
        for (int mask = 1; mask < 16; mask <<= 1) {
          dss[mi][r] += __shfl_xor(dss[mi][r], mask);
          dsd[mi][r] += __shfl_xor(dsd[mi][r], mask);
        }
        if (lr == 0) {
          int rowloc = mi * 16 + lg * 4 + r;
          sm.g.sas[wave][rowloc] = dss[mi][r];
          sm.g.sad[wave][rowloc] = dsd[mi][r];
        }
      }
    __syncthreads();
    if (tid < 32) {
      float s = sm.g.sas[0][tid] + sm.g.sas[1][tid] + sm.g.sas[2][tid] + sm.g.sas[3][tid];
      float d = sm.g.sad[0][tid] + sm.g.sad[1][tid] + sm.g.sad[2][tid] + sm.g.sad[3][tid];
      o_as[m0 + tid] = s;
      o_ad[m0 + tid] = d;
    }
  }
}

template <int VEC>
__device__ void d_gcn_agg(SMemU& sm, int c, const unsigned short* h, const int* rowptr,
                          const int* csr_src, const float* dinv, float* out) {
  constexpr int F = 64 * VEC;
  __syncthreads();
  int tid = threadIdx.x, wv = tid >> 6, ln = tid & 63;
  float dc = dinv[c];
  int r0 = rowptr[c], r1 = rowptr[c + 1];
  float acc[VEC] = {};
  for (int base = r0; base < r1; base += 128) {
    int nb = min(128, r1 - base);
    __syncthreads();
    if (tid < nb) { int s = csr_src[base + tid]; sm.a.sld[tid] = s; sm.a.wld[tid] = dinv[s]; }
    __syncthreads();
    for (int i = wv; i < nb; i += 4) {
      float w = sm.a.wld[i];
      const unsigned short* p = h + (size_t)sm.a.sld[i] * F + ln * VEC;
      if (VEC == 2) {
        ushort2 v = *reinterpret_cast<const ushort2*>(p);
        acc[0] += bf2f(v.x) * w; acc[1] += bf2f(v.y) * w;
      } else {
        ushort4 v = *reinterpret_cast<const ushort4*>(p);
        acc[0] += bf2f(v.x) * w; acc[1] += bf2f(v.y) * w;
        acc[2] += bf2f(v.z) * w; acc[3] += bf2f(v.w) * w;
      }
    }
  }
  if (wv) {
#pragma unroll
    for (int j = 0; j < VEC; j++) sm.a.red[wv - 1][ln * VEC + j] = acc[j];
  }
  __syncthreads();
  if (wv == 0) {
    const unsigned short* pc = h + (size_t)c * F + ln * VEC;
#pragma unroll
    for (int j = 0; j < VEC; j++) {
      acc[j] += sm.a.red[0][ln * VEC + j] + sm.a.red[1][ln * VEC + j] + sm.a.red[2][ln * VEC + j];
      acc[j] += bf2f(pc[j]) * dc;
      out[(size_t)c * F + ln * VEC + j] = acc[j] * dc;
    }
  }
}

__device__ void d_sage_agg(SMemU& sm, int c, const unsigned short* x, const int* rowptr,
                           const int* csr_src, unsigned short* out) {
  __syncthreads();
  int tid = threadIdx.x, wv = tid >> 6, ln = tid & 63;
  int r0 = rowptr[c], r1 = rowptr[c + 1];
  float a0 = 0.f, a1 = 0.f;
  for (int base = r0; base < r1; base += 128) {
    int nb = min(128, r1 - base);
    __syncthreads();
    if (tid < nb) sm.a.sld[tid] = csr_src[base + tid];
    __syncthreads();
    for (int i = wv; i < nb; i += 4) {
      ushort2 v = *reinterpret_cast<const ushort2*>(x + (size_t)sm.a.sld[i] * 256 + ln * 2);
      a0 += bf2f(v.x); a1 += bf2f(v.y);
    }
  }
  if (wv) { sm.a.red[wv - 1][ln * 2] = a0; sm.a.red[wv - 1][ln * 2 + 1] = a1; }
  __syncthreads();
  if (wv == 0) {
    a0 += sm.a.red[0][ln * 2] + sm.a.red[1][ln * 2] + sm.a.red[2][ln * 2];
    a1 += sm.a.red[0][ln * 2 + 1] + sm.a.red[1][ln * 2 + 1] + sm.a.red[2][ln * 2 + 1];
    float inv = 1.f / fmaxf((float)(r1 - r0), 1.f);
    ushort2 o; o.x = f2bf(a0 * inv); o.y = f2bf(a1 * inv);
    *reinterpret_cast<ushort2*>(out + (size_t)c * 256 + ln * 2) = o;
  }
}

__device__ void d_cheb_agg(SMemU& sm, int c, const unsigned short* x, const int* rowptr,
                           const int* csr_src, const float* dinv0, unsigned short* out) {
  __syncthreads();
  int tid = threadIdx.x, wv = tid >> 6, ln = tid & 63;
  int r0 = rowptr[c], r1 = rowptr[c + 1];
  float a0 = 0.f, a1 = 0.f;
  for (int base = r0; base < r1; base += 128) {
    int nb = min(128, r1 - base);
    __syncthreads();
    if (tid < nb) { int s = csr_src[base + tid]; sm.a.sld[tid] = s; sm.a.wld[tid] = dinv0[s]; }
    __syncthreads();
    for (int i = wv; i < nb; i += 4) {
      float w = sm.a.wld[i];
      ushort2 v = *reinterpret_cast<const ushort2*>(x + (size_t)sm.a.sld[i] * 256 + ln * 2);
      a0 += bf2f(v.x) * w; a1 += bf2f(v.y) * w;
    }
  }
  if (wv) { sm.a.red[wv - 1][ln * 2] = a0; sm.a.red[wv - 1][ln * 2 + 1] = a1; }
  __syncthreads();
  if (wv == 0) {
    a0 += sm.a.red[0][ln * 2] + sm.a.red[1][ln * 2] + sm.a.red[2][ln * 2];
    a1 += sm.a.red[0][ln * 2 + 1] + sm.a.red[1][ln * 2 + 1] + sm.a.red[2][ln * 2 + 1];
    float s = -dinv0[c];
    ushort2 o; o.x = f2bf(a0 * s); o.y = f2bf(a1 * s);
    *reinterpret_cast<ushort2*>(out + (size_t)c * 256 + ln * 2) = o;
  }
}

__device__ void d_gat_agg(SMemU& sm, int c, const unsigned short* h, const int* rowptr,
                          const int* csr_src, const float* a_s, const float* a_d,
                          const float* bias, unsigned short* out) {
  __syncthreads();
  int tid = threadIdx.x, wv = tid >> 6, ln = tid & 63;
  int r0 = rowptr[c], r1 = rowptr[c + 1];
  float adc = a_d[c];
  float es = a_s[c] + adc;
  es = es >= 0.f ? es : 0.2f * es;
  float m = es;
  for (int i = r0 + tid; i < r1; i += 256) {
    float v = a_s[csr_src[i]] + adc;
    m = fmaxf(m, v >= 0.f ? v : 0.2f * v);
  }
  sm.a.smax[tid] = m;
  __syncthreads();
  for (int sft = 128; sft; sft >>= 1) {
    if (tid < sft) sm.a.smax[tid] = fmaxf(sm.a.smax[tid], sm.a.smax[tid + sft]);
    __syncthreads();
  }
  m = sm.a.smax[0];
  float a0 = 0.f, a1 = 0.f, den = 0.f;
  for (int base = r0; base < r1; base += 128) {
    int nb = min(128, r1 - base);
    __syncthreads();
    if (tid < nb) {
      int s = csr_src[base + tid];
      sm.a.sld[tid] = s;
      float v = a_s[s] + adc;
      v = v >= 0.f ? v : 0.2f * v;
      sm.a.eld[tid] = expf(v - m);
    }
    __syncthreads();
    for (int i = wv; i < nb; i += 4) {
      float w = sm.a.eld[i];
      den += w;
      ushort2 v = *reinterpret_cast<const ushort2*>(h + (size_t)sm.a.sld[i] * 128 + ln * 2);
      a0 += w * bf2f(v.x); a1 += w * bf2f(v.y);
    }
  }
  if (wv) {
    sm.a.red[wv - 1][ln * 2] = a0; sm.a.red[wv - 1][ln * 2 + 1] = a1;
    if (ln == 0) sm.a.sden[wv] = den;
  }
  __syncthreads();
  if (wv == 0) {
    a0 += sm.a.red[0][ln * 2] + sm.a.red[1][ln * 2] + sm.a.red[2][ln * 2];
    a1 += sm.a.red[0][ln * 2 + 1] + sm.a.red[1][ln * 2 + 1] + sm.a.red[2][ln * 2 + 1];
    den += sm.a.sden[1] + sm.a.sden[2] + sm.a.sden[3];
    float ws = expf(es - m);
    den += ws;
    ushort2 xc = *reinterpret_cast<const ushort2*>(h + (size_t)c * 128 + ln * 2);
    a0 += ws * bf2f(xc.x); a1 += ws * bf2f(xc.y);
    float inv = 1.f / den;
    float v0 = a0 * inv + bias[ln * 2];
    float v1 = a1 * inv + bias[ln * 2 + 1];
    v0 = v0 > 0.f ? v0 : expm1f(v0);
    v1 = v1 > 0.f ? v1 : expm1f(v1);
    ushort2 o; o.x = f2bf(v0); o.y = f2bf(v1);
    *reinterpret_cast<ushort2*>(out + (size_t)c * 128 + ln * 2) = o;
  }
}

__device__ void d_bn_stats(int blk, const float* x, float* psum, float* psq, int F) {
  int tid = threadIdx.x;
  int f = tid & (F - 1);
  int rstep = 256 / F;
  int r0 = tid / F;
  int base = blk * 64;
  float s = 0.f, s2 = 0.f;
  for (int rr = r0; rr < 64; rr += rstep) {
    float v = x[(size_t)(base + rr) * F + f];
    s += v;
    s2 += v * v;
  }
  int slot = blk * rstep + r0;
  psum[(size_t)slot * F + f] = s;
  psq[(size_t)slot * F + f] = s2;
}

__device__ void d_bn_apply2(SMemU& sm, int blk, const float* x, const float* psum,
                            const float* psq, const float* g, const float* be,
                            unsigned short* y, int ldY) {
  __syncthreads();
  int tid = threadIdx.x;
  if (tid < 128) {
    float s = 0.f, s2 = 0.f;
    for (int i = 0; i < 128; i++) {
      s += psum[(size_t)i * 128 + tid];
      s2 += psq[(size_t)i * 128 + tid];
    }
    float invM = 1.f / (float)NN;
    float mu = s * invM;
    float var = s2 * invM - mu * mu;
    float scv = g[tid] * rsqrtf(var + 1e-5f);
    sm.bn.sc[tid] = scv;
    sm.bn.sh[tid] = be[tid] - mu * scv;
  }
  __syncthreads();
  int f = tid & 127, rhalf = tid >> 7;
  int row0 = blk * 16;
  for (int rr = 0; rr < 8; rr++) {
    int row = row0 + rr * 2 + rhalf;
    float v = fmaxf(x[(size_t)row * 128 + f] * sm.bn.sc[f] + sm.bn.sh[f], 0.f);
    y[(size_t)row * ldY + f] = f2bf(v);
  }
}

// ---------------- trunk mega-kernel (cooperative) ----------------
struct TrunkArgs {
  const unsigned short *x2b, *g1t, *g2t, *sgt, *cht, *a1t, *a2t;
  unsigned short *h1b, *hb, *catS, *catC, *xb2, *xa2, *xb3;
  float *agg, *psum, *psq, *a_s, *a_d;
  const int *rowptr, *csr_src;
  const float *dinvA, *dinv0;
  const float *bn1_g, *bn1_b, *bn2_g, *bn2_b;
  const float *sage_bl, *cheb_b;
  const float *gat1_as, *gat1_ad, *gat1_b, *gat2_as, *gat2_ad, *gat2_b;
};

__global__ __launch_bounds__(256, 4) void k_trunk(TrunkArgs t) {
  cg::grid_group grid = cg::this_grid();
  __shared__ SMemU sm;
  int b = blockIdx.x;
  int gd = gridDim.x;
  // S1: GCN1 GEMM (512->256), 256 tiles of grid (2,128)
  for (int tb = b; tb < 256; tb += gd)
    d_bgemm_s<0>(sm, tb & 1, tb >> 1, t.x2b, t.g1t, nullptr, t.h1b, 256, 512, 0,
                 nullptr, nullptr, nullptr, nullptr, nullptr, nullptr, nullptr, nullptr);
  grid.sync();
  // S2: gcn_agg F=256
  for (int c = b; c < NN; c += gd) d_gcn_agg<4>(sm, c, t.h1b, t.rowptr, t.csr_src, t.dinvA, t.agg);
  grid.sync();
  // S3: bn stats F=256
  for (int bb = b; bb < 64; bb += gd) d_bn_stats(bb, t.agg, t.psum, t.psq, 256);
  grid.sync();
  // S4: GCN2 GEMM (256->128), bn1 final+affine+relu fused; 128 tiles
  for (int tb = b; tb < 128; tb += gd)
    d_bgemm_s<1>(sm, 0, tb, t.agg, t.g2t, nullptr, t.hb, 128, 256, 0,
                 t.psum, t.psq, t.bn1_g, t.bn1_b, nullptr, nullptr, nullptr, nullptr);
  grid.sync();
  // S5: gcn_agg F=128
  for (int c = b; c < NN; c += gd) d_gcn_agg<2>(sm, c, t.hb, t.rowptr, t.csr_src, t.dinvA, t.agg);
  grid.sync();
  // S6: bn stats F=128
  for (int bb = b; bb < 64; bb += gd) d_bn_stats(bb, t.agg, t.psum, t.psq, 128);
  grid.sync();
  // S7: bn2 final+apply -> catS right half
  for (int bb = b; bb < 256; bb += gd)
    d_bn_apply2(sm, bb, t.agg, t.psum, t.psq, t.bn2_g, t.bn2_b, t.catS + 128, 256);
  grid.sync();
  // S8: sage_agg -> catS left
  for (int c = b; c < NN; c += gd) d_sage_agg(sm, c, t.catS + 128, t.rowptr, t.csr_src, t.catS);
  grid.sync();
  // S9: SAGE fused GEMM -> catC left
  for (int tb = b; tb < 128; tb += gd)
    d_bgemm_s<0>(sm, 0, tb, t.catS, t.sgt, t.sage_bl, t.catC, 256, 256, 1,
                 nullptr, nullptr, nullptr, nullptr, nullptr, nullptr, nullptr, nullptr);
  grid.sync();
  // S10: cheb_agg -> catC right
  for (int c = b; c < NN; c += gd) d_cheb_agg(sm, c, t.catC, t.rowptr, t.csr_src, t.dinv0, t.catC + 128);
  grid.sync();
  // S11: Cheb fused GEMM -> xb2
  for (int tb = b; tb < 128; tb += gd)
    d_bgemm_s<0>(sm, 0, tb, t.catC, t.cht, t.cheb_b, t.xb2, 128, 256, 1,
                 nullptr, nullptr, nullptr, nullptr, nullptr, nullptr, nullptr, nullptr);
  grid.sync();
  // S12: GAT1 GEMM + dots
  for (int tb = b; tb < 128; tb += gd)
    d_bgemm_s<2>(sm, 0, tb, t.xb2, t.a1t, nullptr, t.hb, 128, 128, 0,
                 nullptr, nullptr, nullptr, nullptr, t.gat1_as, t.gat1_ad, t.a_s, t.a_d);
  grid.sync();
  // S13: gat_agg -> xa2
  for (int c = b; c < NN; c += gd)
    d_gat_agg(sm, c, t.hb, t.rowptr, t.csr_src, t.a_s, t.a_d, t.gat1_b, t.xa2);
  grid.sync();
  // S14: GAT2 GEMM + dots
  for (int tb = b; tb < 128; tb += gd)
    d_bgemm_s<2>(sm, 0, tb, t.xa2, t.a2t, nullptr, t.hb, 128, 128, 0,
                 nullptr, nullptr, nullptr, nullptr, t.gat2_as, t.gat2_ad, t.a_s, t.a_d);
  grid.sync();
  // S15: gat_agg -> xb3
  for (int c = b; c < NN; c += gd)
    d_gat_agg(sm, c, t.hb, t.rowptr, t.csr_src, t.a_s, t.a_d, t.gat2_b, t.xb3);
}

// ---------------- CSR build ----------------
__global__ void k_scan4096(const int* __restrict__ deg1, const int* __restrict__ deg0,
                           int* __restrict__ rowptr, int* __restrict__ cursor,
                           float* __restrict__ dinvA, float* __restrict__ dinv0) {
  __shared__ int s[1024];
  int t = threadIdx.x;
  int4 d = *reinterpret_cast<const int4*>(deg1 + t * 4);
  float4 dv = {rsqrtf((float)(d.x + 1)), rsqrtf((float)(d.y + 1)),
               rsqrtf((float)(d.z + 1)), rsqrtf((float)(d.w + 1))};
  *reinterpret_cast<float4*>(dinvA + t * 4) = dv;
  int4 d0 = *reinterpret_cast<const int4*>(deg0 + t * 4);
  float4 dv0 = {d0.x > 0 ? rsqrtf((float)d0.x) : 0.f, d0.y > 0 ? rsqrtf((float)d0.y) : 0.f,
                d0.z > 0 ? rsqrtf((float)d0.z) : 0.f, d0.w > 0 ? rsqrtf((float)d0.w) : 0.f};
  *reinterpret_cast<float4*>(dinv0 + t * 4) = dv0;
  int sum = d.x + d.y + d.z + d.w;
  s[t] = sum;
  __syncthreads();
  for (int off = 1; off < 1024; off <<= 1) {
    int x = (t >= off) ? s[t - off] : 0;
    __syncthreads();
    s[t] += x;
    __syncthreads();
  }
  int base = s[t] - sum;  // exclusive
  int4 o;
  o.x = base; o.y = base + d.x; o.z = o.y + d.y; o.w = o.z + d.z;
  *reinterpret_cast<int4*>(rowptr + t * 4) = o;
  *reinterpret_cast<int4*>(cursor + t * 4) = o;
  if (t == 1023) rowptr[4096] = base + sum;
}

__global__ void k_fill(const int* __restrict__ ei0, const int* __restrict__ ei1,
                       int* __restrict__ cursor, int* __restrict__ csr_src) {
  int e = blockIdx.x * blockDim.x + threadIdx.x;
  if (e < NE) {
    int pos = atomicAdd(&cursor[ei1[e]], 1);
    csr_src[pos] = ei0[e];
  }
}

// ---------------- launch ----------------
static inline int cdiv(int a, int b) { return (a + b - 1) / b; }

extern "C" void kernel_launch(void* const* d_in, const int* in_sizes, int n_in,
                              void* d_out, int out_size, void* d_ws, size_t ws_size,
                              hipStream_t stream) {
  const int* ei = (const int*)d_in[0];
  const int* ei0 = ei;
  const int* ei1 = ei + NE;
  const int* node_x = (const int*)d_in[1];
  const float* user_w = (const float*)d_in[2];
  const float* item_w = (const float*)d_in[3];
  const float* mlp_w1 = (const float*)d_in[4];
  const float* mlp_b1 = (const float*)d_in[5];
  const float* mlp_w2 = (const float*)d_in[6];
  const float* mlp_b2 = (const float*)d_in[7];
  const float* gcn_w1 = (const float*)d_in[8];
  // d_in[9] gcn_b1 / d_in[13] gcn_b2: cancelled by batch_norm mean subtraction
  const float* bn1_g = (const float*)d_in[10];
  const float* bn1_b = (const float*)d_in[11];
  const float* gcn_w2 = (const float*)d_in[12];
  const float* bn2_g = (const float*)d_in[14];
  const float* bn2_b = (const float*)d_in[15];
  const float* sage_wl = (const float*)d_in[16];
  const float* sage_bl = (const float*)d_in[17];
  const float* sage_wr = (const float*)d_in[18];
  const float* cheb_w0 = (const float*)d_in[19];
  const float* cheb_w1 = (const float*)d_in[20];
  const float* cheb_b = (const float*)d_in[21];
  const float* gat1_w = (const float*)d_in[22];
  const float* gat1_as = (const float*)d_in[23];
  const float* gat1_ad = (const float*)d_in[24];
  const float* gat1_b = (const float*)d_in[25];
  const float* gat2_w = (const float*)d_in[26];
  const float* gat2_as = (const float*)d_in[27];
  const float* gat2_ad = (const float*)d_in[28];
  const float* gat2_b = (const float*)d_in[29];
  const float* pred_w = (const float*)d_in[30];
  const float* pred_b = (const float*)d_in[31];

  // ---- workspace layout ----
  char* w = (char*)d_ws;
  size_t off = 0;
  auto alloc = [&](size_t bytes) -> char* {
    char* p = w + off;
    off = (off + bytes + 255) & ~(size_t)255;
    return p;
  };
  unsigned short* x0b = (unsigned short*)alloc((size_t)NN * 128 * 2);
  unsigned short* x1b = (unsigned short*)alloc((size_t)NN * 1024 * 2);
  unsigned short* x2b = (unsigned short*)alloc((size_t)NN * 512 * 2);
  unsigned short* h1b = (unsigned short*)alloc((size_t)NN * 256 * 2);
  unsigned short* catS = (unsigned short*)alloc((size_t)NN * 256 * 2);  // [sage_agg | xb]
  unsigned short* catC = (unsigned short*)alloc((size_t)NN * 256 * 2);  // [xa | cheb_agg]
  unsigned short* xb2 = (unsigned short*)alloc((size_t)NN * 128 * 2);
  unsigned short* hb = (unsigned short*)alloc((size_t)NN * 128 * 2);
  unsigned short* xa2 = (unsigned short*)alloc((size_t)NN * 128 * 2);
  unsigned short* xb3 = (unsigned short*)alloc((size_t)NN * 128 * 2);
  float* agg = (float*)alloc((size_t)NN * 256 * 4);
  unsigned short* w1t = (unsigned short*)alloc((size_t)1024 * 128 * 2);
  unsigned short* w2t = (unsigned short*)alloc((size_t)512 * 1024 * 2);
  unsigned short* g1t = (unsigned short*)alloc((size_t)256 * 512 * 2);
  unsigned short* g2t = (unsigned short*)alloc((size_t)128 * 256 * 2);
  unsigned short* sgt = (unsigned short*)alloc((size_t)128 * 256 * 2);  // [Wl;Wr]^T
  unsigned short* cht = (unsigned short*)alloc((size_t)128 * 256 * 2);  // [W0;W1]^T
  unsigned short* a1t = (unsigned short*)alloc((size_t)128 * 128 * 2);
  unsigned short* a2t = (unsigned short*)alloc((size_t)128 * 128 * 2);
  unsigned short* predT = (unsigned short*)alloc((size_t)NPAD * 128 * 2);
  int* deg0 = (int*)alloc(NN * 4);
  int* deg1 = (int*)alloc(NN * 4);  // contiguous after deg0
  int* rowptr = (int*)alloc((NN + 1) * 4);
  int* cursor = (int*)alloc(NN * 4);
  int* csr_src = (int*)alloc(NE * 4);
  float* dinvA = (float*)alloc(NN * 4);
  float* dinv0 = (float*)alloc(NN * 4);
  float* a_s = (float*)alloc(NN * 4);
  float* a_d = (float*)alloc(NN * 4);
  float* psum = (float*)alloc(16384 * 4);
  float* psq = (float*)alloc(16384 * 4);

  // ---- fused launch 0: weight cvt + degree count + gather ----
  CvtArgs ca;
  int t0 = 0;
  auto mkd = [&](int i, const float* src, unsigned short* dst, int K, int N, int ld, int koff,
                 int ntx) {
    ca.d[i] = {src, dst, K, N, ld, koff, t0, ntx};
    t0 += ntx * (K / 32);
  };
  mkd(0, mlp_w1, w1t, 128, 1024, 128, 0, 32);
  mkd(1, mlp_w2, w2t, 1024, 512, 1024, 0, 16);
  mkd(2, gcn_w1, g1t, 512, 256, 512, 0, 8);
  mkd(3, gcn_w2, g2t, 256, 128, 256, 0, 4);
  mkd(4, sage_wl, sgt, 128, 128, 256, 0, 4);
  mkd(5, sage_wr, sgt, 128, 128, 256, 128, 4);
  mkd(6, cheb_w0, cht, 128, 128, 256, 0, 4);
  mkd(7, cheb_w1, cht, 128, 128, 256, 128, 4);
  mkd(8, gat1_w, a1t, 128, 128, 128, 0, 4);
  mkd(9, gat2_w, a2t, 128, 128, 128, 0, 4);
  mkd(10, pred_w, predT, 128, NCLS, 128, 0, NPAD / 32);

  hipMemsetAsync(deg0, 0, 2 * NN * 4, stream);
  k_fused0<<<t0 + 512 + NN / 2, 256, 0, stream>>>(ca, t0, ei, deg0, deg1, node_x, user_w,
                                                  item_w, x0b);
  k_scan4096<<<1, 1024, 0, stream>>>(deg1, deg0, rowptr, cursor, dinvA, dinv0);
  k_fill<<<cdiv(NE, 256), 256, 0, stream>>>(ei0, ei1, cursor, csr_src);

  // ---- MLP GEMMs ----
  k_bgemm<1><<<dim3(8, 32), 256, 0, stream>>>(x0b, w1t, mlp_b1, x1b, 1024, 128, 1);
  k_bgemm<1><<<dim3(4, 32), 256, 0, stream>>>(x1b, w2t, mlp_b2, x2b, 512, 1024, 1);

  // ---- trunk: single cooperative launch (GCN1 ... GAT2) ----
  TrunkArgs ta;
  ta.x2b = x2b; ta.g1t = g1t; ta.g2t = g2t; ta.sgt = sgt; ta.cht = cht; ta.a1t = a1t; ta.a2t = a2t;
  ta.h1b = h1b; ta.hb = hb; ta.catS = catS; ta.catC = catC; ta.xb2 = xb2; ta.xa2 = xa2; ta.xb3 = xb3;
  ta.agg = agg; ta.psum = psum; ta.psq = psq; ta.a_s = a_s; ta.a_d = a_d;
  ta.rowptr = rowptr; ta.csr_src = csr_src;
  ta.dinvA = dinvA; ta.dinv0 = dinv0;
  ta.bn1_g = bn1_g; ta.bn1_b = bn1_b; ta.bn2_g = bn2_g; ta.bn2_b = bn2_b;
  ta.sage_bl = sage_bl; ta.cheb_b = cheb_b;
  ta.gat1_as = gat1_as; ta.gat1_ad = gat1_ad; ta.gat1_b = gat1_b;
  ta.gat2_as = gat2_as; ta.gat2_ad = gat2_ad; ta.gat2_b = gat2_b;
  int nb = 0;
  hipOccupancyMaxActiveBlocksPerMultiprocessor(&nb, k_trunk, 256, 0);
  if (nb < 1) nb = 1;
  int gblocks = nb * 256;  // 256 CUs
  if (gblocks > 2048) gblocks = 2048;
  void* kargs[] = {(void*)&ta};
  hipLaunchCooperativeKernel(k_trunk, dim3(gblocks), dim3(256), kargs, 0, stream);

  // ---- final prediction GEMM (r8 form) ----
  k_pred_gemm<<<dim3(NPAD / 128, 4), 256, 0, stream>>>(xb3, predT, pred_b, (float*)d_out);
}

// Round 13
// 466.832 us; speedup vs baseline: 2.8175x; 2.8175x over previous
//
#include <hip/hip_runtime.h>
#include <math.h>

#define NN 4096
#define NE 131072
#define NCLS 41476
#define NPAD 41600  // 325 * 128

typedef __attribute__((ext_vector_type(8))) unsigned short ushort8;
typedef __attribute__((ext_vector_type(8))) __bf16 bf16x8;
typedef __attribute__((ext_vector_type(4))) float f32x4;

__device__ __forceinline__ unsigned short f2bf(float f) {
  unsigned u = __float_as_uint(f);
  unsigned r = u + 0x7fffu + ((u >> 16) & 1u);  // RNE
  return (unsigned short)(r >> 16);
}
__device__ __forceinline__ float bf2f(unsigned short u) {
  return __uint_as_float(((unsigned)u) << 16);
}

// async global->LDS, 16B per lane; LDS dest must be wave-uniform base (lane x 16 implicit)
__device__ __forceinline__ void gload16(const void* g, void* l) {
  __builtin_amdgcn_global_load_lds(
      (const __attribute__((address_space(1))) unsigned int*)g,
      (__attribute__((address_space(3))) unsigned int*)l, 16, 0, 0);
}

// ---------------- fused: weight transposes + edge degree count + embedding gather ----------------
struct CvtDesc { const float* src; unsigned short* dst; int K, N, ld, koff, tile0, ntx; };
struct CvtArgs { CvtDesc d[11]; };

__global__ void k_fused0(CvtArgs a, int cvtBlocks, const int* __restrict__ ei,
                         int* __restrict__ deg0, int* __restrict__ deg1,
                         const int* __restrict__ node_x, const float* __restrict__ uw,
                         const float* __restrict__ iw, unsigned short* __restrict__ x0) {
  int b = blockIdx.x;
  int tid = threadIdx.x;
  if (b < cvtBlocks) {
    __shared__ float s[32][33];
    int di = 0;
#pragma unroll
    for (int i = 1; i < 11; i++)
      if (a.d[i].tile0 <= b) di = i;
    const CvtDesc dd = a.d[di];
    int t = b - dd.tile0;
    int n0 = (t % dd.ntx) * 32, k0 = (t / dd.ntx) * 32;
    int c = tid & 31, r8 = tid >> 5;
#pragma unroll
    for (int r = 0; r < 4; r++) {
      int k = k0 + r8 + r * 8, n = n0 + c;
      s[r8 + r * 8][c] = (n < dd.N) ? dd.src[(size_t)k * dd.N + n] : 0.f;
    }
    __syncthreads();
#pragma unroll
    for (int r = 0; r < 4; r++) {
      int n = n0 + r8 + r * 8, k = k0 + c;
      dd.dst[(size_t)n * dd.ld + dd.koff + k] = f2bf(s[c][r8 + r * 8]);
    }
  } else if (b < cvtBlocks + 512) {
    int bid = b - cvtBlocks;
    for (int i = bid * 256 + tid; i < 2 * NE; i += 512 * 256) {
      int v = ei[i];
      atomicAdd((i < NE ? deg0 : deg1) + v, 1);
    }
  } else {
    int nb = b - cvtBlocks - 512;     // 2048 blocks, 2 nodes each
    int n = nb * 2 + (tid >> 7);
    int t = tid & 127;
    int u = node_x[n * 2], it = node_x[n * 2 + 1];
    float v = (t < 64) ? uw[u * 64 + t] : iw[it * 64 + (t - 64)];
    x0[n * 128 + t] = f2bf(v);
  }
}

// ---------------- bf16 MFMA GEMM, 128x128 tile, direct-store epilogue ----------------
template <int OUTBF>
__global__ __launch_bounds__(256) void k_bgemm(const unsigned short* __restrict__ A,
                                               const unsigned short* __restrict__ Bt,
                                               const float* __restrict__ bias,
                                               void* __restrict__ Cv, int N, int K, int relu) {
  __shared__ unsigned short As[128 * 128];
  __shared__ unsigned short Bs[128 * 128];
  int m0 = blockIdx.y * 128;
  int n0 = blockIdx.x * 128;
  int tid = threadIdx.x;
  int wave = tid >> 6, lane = tid & 63;
  int wm = (wave >> 1) * 64, wn = (wave & 1) * 64;
  int lr = lane & 15, lg = lane >> 4;
  f32x4 acc[4][4] = {};
  for (int k0 = 0; k0 < K; k0 += 128) {
#pragma unroll
    for (int i = 0; i < 8; i++) {
      int idx = tid + i * 256;
      int row = idx >> 4, ku = idx & 15;
      int sw = (ku ^ (row & 7)) * 8;
      *reinterpret_cast<ushort8*>(As + row * 128 + sw) =
          *reinterpret_cast<const ushort8*>(A + (size_t)(m0 + row) * K + k0 + ku * 8);
      *reinterpret_cast<ushort8*>(Bs + row * 128 + sw) =
          *reinterpret_cast<const ushort8*>(Bt + (size_t)(n0 + row) * K + k0 + ku * 8);
    }
    __syncthreads();
#pragma unroll
    for (int kk = 0; kk < 4; kk++) {
      bf16x8 af[4], bfr[4];
#pragma unroll
      for (int mi = 0; mi < 4; mi++) {
        int row = wm + mi * 16 + lr;
        af[mi] = __builtin_bit_cast(
            bf16x8, *reinterpret_cast<const ushort8*>(As + row * 128 + (((kk * 4 + lg) ^ (row & 7)) * 8)));
        int col = wn + mi * 16 + lr;
        bfr[mi] = __builtin_bit_cast(
            bf16x8, *reinterpret_cast<const ushort8*>(Bs + col * 128 + (((kk * 4 + lg) ^ (col & 7)) * 8)));
      }
#pragma unroll
      for (int mi = 0; mi < 4; mi++)
#pragma unroll
        for (int ni = 0; ni < 4; ni++)
          acc[mi][ni] = __builtin_amdgcn_mfma_f32_16x16x32_bf16(af[mi], bfr[ni], acc[mi][ni], 0, 0, 0);
    }
    __syncthreads();
  }
#pragma unroll
  for (int mi = 0; mi < 4; mi++) {
#pragma unroll
    for (int ni = 0; ni < 4; ni++) {
      int col = n0 + wn + ni * 16 + lr;
      if (col < N) {
        float bv = bias ? bias[col] : 0.f;
#pragma unroll
        for (int r = 0; r < 4; r++) {
          int row = m0 + wm + mi * 16 + lg * 4 + r;
          float v = acc[mi][ni][r] + bv;
          if (relu) v = fmaxf(v, 0.f);
          if (OUTBF)
            ((unsigned short*)Cv)[(size_t)row * N + col] = f2bf(v);
          else
            ((float*)Cv)[(size_t)row * N + col] = v;
        }
      }
    }
  }
}

// ---------------- pred GEMM, N-tile-resident, global_load_lds staging ----------------
// grid (NPAD/128, 4): block = (N-tile ci, M-quarter), 8 M-tiles per block.
// LDS dest linear; XOR swizzle applied on the GLOBAL source address (involution), read side unchanged.
__global__ __launch_bounds__(256) void k_pred_gemm(const unsigned short* __restrict__ A,
                                                   const unsigned short* __restrict__ Bt,
                                                   const float* __restrict__ bias,
                                                   float* __restrict__ C) {
  __shared__ unsigned short As[128 * 128];
  __shared__ unsigned short Bs[128 * 128];
  int n0 = blockIdx.x * 128;
  int tid = threadIdx.x;
  int wave = tid >> 6, lane = tid & 63;
  int wm = (wave >> 1) * 64, wn = (wave & 1) * 64;
  int lr = lane & 15, lg = lane >> 4;
  // stage B once (K = 128 exactly): LDS unit idx holds global unit (row, u^(row&7))
#pragma unroll
  for (int i = 0; i < 8; i++) {
    int idx = tid + i * 256;
    int row = idx >> 4, u = idx & 15;
    gload16(Bt + (size_t)(n0 + row) * 128 + ((u ^ (row & 7)) * 8),
            Bs + ((size_t)i * 256 + wave * 64) * 8);
  }
  float bv[4];
  int colv[4];
#pragma unroll
  for (int ni = 0; ni < 4; ni++) {
    colv[ni] = n0 + wn + ni * 16 + lr;
    bv[ni] = (colv[ni] < NCLS) ? bias[colv[ni]] : 0.f;
  }
  int mt0 = blockIdx.y * 8;
  for (int mt = mt0; mt < mt0 + 8; ++mt) {
    int m0 = mt * 128;
    __syncthreads();  // prev-iter As consumers done; drains outstanding gload (vmcnt)
#pragma unroll
    for (int i = 0; i < 8; i++) {
      int idx = tid + i * 256;
      int row = idx >> 4, u = idx & 15;
      gload16(A + (size_t)(m0 + row) * 128 + ((u ^ (row & 7)) * 8),
              As + ((size_t)i * 256 + wave * 64) * 8);
    }
    __syncthreads();  // As (and first-iter Bs) staged
    f32x4 acc[4][4] = {};
#pragma unroll
    for (int kk = 0; kk < 4; kk++) {
      bf16x8 af[4], bfr[4];
#pragma unroll
      for (int mi = 0; mi < 4; mi++) {
        int row = wm + mi * 16 + lr;
        af[mi] = __builtin_bit_cast(
            bf16x8, *reinterpret_cast<const ushort8*>(As + row * 128 + (((kk * 4 + lg) ^ (row & 7)) * 8)));
        int col = wn + mi * 16 + lr;
        bfr[mi] = __builtin_bit_cast(
            bf16x8, *reinterpret_cast<const ushort8*>(Bs + col * 128 + (((kk * 4 + lg) ^ (col & 7)) * 8)));
      }
#pragma unroll
      for (int mi = 0; mi < 4; mi++)
#pragma unroll
        for (int ni = 0; ni < 4; ni++)
          acc[mi][ni] = __builtin_amdgcn_mfma_f32_16x16x32_bf16(af[mi], bfr[ni], acc[mi][ni], 0, 0, 0);
    }
#pragma unroll
    for (int mi = 0; mi < 4; mi++) {
#pragma unroll
      for (int ni = 0; ni < 4; ni++) {
        if (colv[ni] < NCLS) {
#pragma unroll
          for (int r = 0; r < 4; r++) {
            int row = m0 + wm + mi * 16 + lg * 4 + r;
            C[(size_t)row * NCLS + colv[ni]] = acc[mi][ni][r] + bv[ni];
          }
        }
      }
    }
  }
}

// ---------------- bf16 MFMA GEMM, 32x128 tile; MODE 0=plain 1=bnfinal+affine-fp32-A 2=dots ----------------
template <int MODE>
__global__ __launch_bounds__(256) void k_bgemm_s(const void* __restrict__ Av,
                                                 const unsigned short* __restrict__ Bt,
                                                 const float* __restrict__ bias,
                                                 unsigned short* __restrict__ C, int ldC,
                                                 int K, int relu,
                                                 const float* __restrict__ psum,
                                                 const float* __restrict__ psq,
                                                 const float* __restrict__ bng,
                                                 const float* __restrict__ bnb,
                                                 const float* __restrict__ asrc,
                                                 const float* __restrict__ adst,
                                                 float* __restrict__ o_as,
                                                 float* __restrict__ o_ad) {
  __shared__ unsigned short As[32 * 64];
  __shared__ unsigned short Bs[128 * 64];
  __shared__ float sc[256], sh[256];
  __shared__ float sas[4][32], sad[4][32];
  int m0 = blockIdx.y * 32;
  int n0 = blockIdx.x * 128;
  int tid = threadIdx.x;
  int wave = tid >> 6, lane = tid & 63;
  int wn = wave * 32;
  int lr = lane & 15, lg = lane >> 4;
  if (MODE == 1) {
    if (tid < K) {
      int S = 16384 / K;
      float s = 0.f, s2 = 0.f;
      for (int i = 0; i < S; i++) {
        s += psum[(size_t)i * K + tid];
        s2 += psq[(size_t)i * K + tid];
      }
      float invM = 1.f / (float)NN;
      float mu = s * invM;
      float var = s2 * invM - mu * mu;
      float scv = bng[tid] * rsqrtf(var + 1e-5f);
      sc[tid] = scv;
      sh[tid] = bnb[tid] - mu * scv;
    }
    __syncthreads();
  }
  f32x4 acc[2][2] = {};
  for (int k0 = 0; k0 < K; k0 += 64) {
    {
      int row = tid >> 3, uu = tid & 7, sw = (uu ^ (row & 7)) * 8;
      if (MODE == 1) {
        const float* Af = (const float*)Av;
        const float* p = Af + (size_t)(m0 + row) * K + k0 + uu * 8;
        float4 p0 = *reinterpret_cast<const float4*>(p);
        float4 p1 = *reinterpret_cast<const float4*>(p + 4);
        int kb = k0 + uu * 8;
        float pv[8] = {p0.x, p0.y, p0.z, p0.w, p1.x, p1.y, p1.z, p1.w};
        ushort8 o;
#pragma unroll
        for (int j = 0; j < 8; j++) o[j] = f2bf(fmaxf(pv[j] * sc[kb + j] + sh[kb + j], 0.f));
        *reinterpret_cast<ushort8*>(As + row * 64 + sw) = o;
      } else {
        *reinterpret_cast<ushort8*>(As + row * 64 + sw) =
            *reinterpret_cast<const ushort8*>((const unsigned short*)Av + (size_t)(m0 + row) * K + k0 + uu * 8);
      }
    }
#pragma unroll
    for (int i = 0; i < 4; i++) {
      int idx = tid + i * 256;
      int row = idx >> 3, uu = idx & 7, sw = (uu ^ (row & 7)) * 8;
      *reinterpret_cast<ushort8*>(Bs + row * 64 + sw) =
          *reinterpret_cast<const ushort8*>(Bt + (size_t)(n0 + row) * K + k0 + uu * 8);
    }
    __syncthreads();
#pragma unroll
    for (int kk = 0; kk < 2; kk++) {
      bf16x8 af[2], bfr[2];
#pragma unroll
      for (int mi = 0; mi < 2; mi++) {
        int row = mi * 16 + lr;
        af[mi] = __builtin_bit_cast(
            bf16x8, *reinterpret_cast<const ushort8*>(As + row * 64 + (((kk * 4 + lg) ^ (row & 7)) * 8)));
        int col = wn + mi * 16 + lr;
        bfr[mi] = __builtin_bit_cast(
            bf16x8, *reinterpret_cast<const ushort8*>(Bs + col * 64 + (((kk * 4 + lg) ^ (col & 7)) * 8)));
      }
#pragma unroll
      for (int mi = 0; mi < 2; mi++)
#pragma unroll
        for (int ni = 0; ni < 2; ni++)
          acc[mi][ni] = __builtin_amdgcn_mfma_f32_16x16x32_bf16(af[mi], bfr[ni], acc[mi][ni], 0, 0, 0);
    }
    __syncthreads();
  }
  float dss[2][4] = {}, dsd[2][4] = {};
#pragma unroll
  for (int mi = 0; mi < 2; mi++) {
#pragma unroll
    for (int ni = 0; ni < 2; ni++) {
      int col = n0 + wn + ni * 16 + lr;
      float bv = bias ? bias[col] : 0.f;
      float ac = (MODE == 2) ? asrc[col] : 0.f;
      float dc = (MODE == 2) ? adst[col] : 0.f;
#pragma unroll
      for (int r = 0; r < 4; r++) {
        int row = m0 + mi * 16 + lg * 4 + r;
        float v = acc[mi][ni][r] + bv;
        if (relu) v = fmaxf(v, 0.f);
        C[(size_t)row * ldC + col] = f2bf(v);
        if (MODE == 2) { dss[mi][r] += v * ac; dsd[mi][r] += v * dc; }
      }
    }
  }
  if (MODE == 2) {
#pragma unroll
    for (int mi = 0; mi < 2; mi++)
#pragma unroll
      for (int r = 0; r < 4; r++) {
#pragma unroll
        for (int mask = 1; mask < 16; mask <<= 1) {
          dss[mi][r] += __shfl_xor(dss[mi][r], mask);
          dsd[mi][r] += __shfl_xor(dsd[mi][r], mask);
        }
        if (lr == 0) {
          int rowloc = mi * 16 + lg * 4 + r;
          sas[wave][rowloc] = dss[mi][r];
          sad[wave][rowloc] = dsd[mi][r];
        }
      }
    __syncthreads();
    if (tid < 32) {
      float s = sas[0][tid] + sas[1][tid] + sas[2][tid] + sas[3][tid];
      float d = sad[0][tid] + sad[1][tid] + sad[2][tid] + sad[3][tid];
      o_as[m0 + tid] = s;
      o_ad[m0 + tid] = d;
    }
  }
}

// ---------------- CSR build ----------------
__global__ void k_scan4096(const int* __restrict__ deg1, const int* __restrict__ deg0,
                           int* __restrict__ rowptr, int* __restrict__ cursor,
                           float* __restrict__ dinvA, float* __restrict__ dinv0) {
  __shared__ int s[1024];
  int t = threadIdx.x;
  int4 d = *reinterpret_cast<const int4*>(deg1 + t * 4);
  float4 dv = {rsqrtf((float)(d.x + 1)), rsqrtf((float)(d.y + 1)),
               rsqrtf((float)(d.z + 1)), rsqrtf((float)(d.w + 1))};
  *reinterpret_cast<float4*>(dinvA + t * 4) = dv;
  int4 d0 = *reinterpret_cast<const int4*>(deg0 + t * 4);
  float4 dv0 = {d0.x > 0 ? rsqrtf((float)d0.x) : 0.f, d0.y > 0 ? rsqrtf((float)d0.y) : 0.f,
                d0.z > 0 ? rsqrtf((float)d0.z) : 0.f, d0.w > 0 ? rsqrtf((float)d0.w) : 0.f};
  *reinterpret_cast<float4*>(dinv0 + t * 4) = dv0;
  int sum = d.x + d.y + d.z + d.w;
  s[t] = sum;
  __syncthreads();
  for (int off = 1; off < 1024; off <<= 1) {
    int x = (t >= off) ? s[t - off] : 0;
    __syncthreads();
    s[t] += x;
    __syncthreads();
  }
  int base = s[t] - sum;  // exclusive
  int4 o;
  o.x = base; o.y = base + d.x; o.z = o.y + d.y; o.w = o.z + d.z;
  *reinterpret_cast<int4*>(rowptr + t * 4) = o;
  *reinterpret_cast<int4*>(cursor + t * 4) = o;
  if (t == 1023) rowptr[4096] = base + sum;
}

__global__ void k_fill(const int* __restrict__ ei0, const int* __restrict__ ei1,
                       int* __restrict__ cursor, int* __restrict__ csr_src) {
  int e = blockIdx.x * blockDim.x + threadIdx.x;
  if (e < NE) {
    int pos = atomicAdd(&cursor[ei1[e]], 1);
    csr_src[pos] = ei0[e];
  }
}

// ---------------- CSR aggregations: 256 thr = 4 waves, edges x4-parallel, vector loads ----------------
template <int VEC>
__global__ void k_gcn_agg(const unsigned short* __restrict__ h, const int* __restrict__ rowptr,
                          const int* __restrict__ csr_src, const float* __restrict__ dinv,
                          float* __restrict__ out) {
  constexpr int F = 64 * VEC;
  __shared__ int sld[128];
  __shared__ float wld[128];
  __shared__ float red[3][64 * VEC];
  int c = blockIdx.x, tid = threadIdx.x, wv = tid >> 6, ln = tid & 63;
  float dc = dinv[c];
  int r0 = rowptr[c], r1 = rowptr[c + 1];
  float acc[VEC] = {};
  for (int base = r0; base < r1; base += 128) {
    int nb = min(128, r1 - base);
    __syncthreads();
    if (tid < nb) { int s = csr_src[base + tid]; sld[tid] = s; wld[tid] = dinv[s]; }
    __syncthreads();
    for (int i = wv; i < nb; i += 4) {
      float w = wld[i];
      const unsigned short* p = h + (size_t)sld[i] * F + ln * VEC;
      if (VEC == 2) {
        ushort2 v = *reinterpret_cast<const ushort2*>(p);
        acc[0] += bf2f(v.x) * w; acc[1] += bf2f(v.y) * w;
      } else {
        ushort4 v = *reinterpret_cast<const ushort4*>(p);
        acc[0] += bf2f(v.x) * w; acc[1] += bf2f(v.y) * w;
        acc[2] += bf2f(v.z) * w; acc[3] += bf2f(v.w) * w;
      }
    }
  }
  if (wv) {
#pragma unroll
    for (int j = 0; j < VEC; j++) red[wv - 1][ln * VEC + j] = acc[j];
  }
  __syncthreads();
  if (wv == 0) {
    const unsigned short* pc = h + (size_t)c * F + ln * VEC;
#pragma unroll
    for (int j = 0; j < VEC; j++) {
      acc[j] += red[0][ln * VEC + j] + red[1][ln * VEC + j] + red[2][ln * VEC + j];
      acc[j] += bf2f(pc[j]) * dc;
      out[(size_t)c * F + ln * VEC + j] = acc[j] * dc;
    }
  }
}

__global__ void k_sage_agg(const unsigned short* __restrict__ x, const int* __restrict__ rowptr,
                           const int* __restrict__ csr_src, unsigned short* __restrict__ out) {
  __shared__ int sld[128];
  __shared__ float red[3][128];
  int c = blockIdx.x, tid = threadIdx.x, wv = tid >> 6, ln = tid & 63;
  int r0 = rowptr[c], r1 = rowptr[c + 1];
  float a0 = 0.f, a1 = 0.f;
  for (int base = r0; base < r1; base += 128) {
    int nb = min(128, r1 - base);
    __syncthreads();
    if (tid < nb) sld[tid] = csr_src[base + tid];
    __syncthreads();
    for (int i = wv; i < nb; i += 4) {
      ushort2 v = *reinterpret_cast<const ushort2*>(x + (size_t)sld[i] * 256 + ln * 2);
      a0 += bf2f(v.x); a1 += bf2f(v.y);
    }
  }
  if (wv) { red[wv - 1][ln * 2] = a0; red[wv - 1][ln * 2 + 1] = a1; }
  __syncthreads();
  if (wv == 0) {
    a0 += red[0][ln * 2] + red[1][ln * 2] + red[2][ln * 2];
    a1 += red[0][ln * 2 + 1] + red[1][ln * 2 + 1] + red[2][ln * 2 + 1];
    float inv = 1.f / fmaxf((float)(r1 - r0), 1.f);
    ushort2 o; o.x = f2bf(a0 * inv); o.y = f2bf(a1 * inv);
    *reinterpret_cast<ushort2*>(out + (size_t)c * 256 + ln * 2) = o;
  }
}

__global__ void k_cheb_agg(const unsigned short* __restrict__ x, const int* __restrict__ rowptr,
                           const int* __restrict__ csr_src, const float* __restrict__ dinv0,
                           unsigned short* __restrict__ out) {
  __shared__ int sld[128];
  __shared__ float wld[128];
  __shared__ float red[3][128];
  int c = blockIdx.x, tid = threadIdx.x, wv = tid >> 6, ln = tid & 63;
  int r0 = rowptr[c], r1 = rowptr[c + 1];
  float a0 = 0.f, a1 = 0.f;
  for (int base = r0; base < r1; base += 128) {
    int nb = min(128, r1 - base);
    __syncthreads();
    if (tid < nb) { int s = csr_src[base + tid]; sld[tid] = s; wld[tid] = dinv0[s]; }
    __syncthreads();
    for (int i = wv; i < nb; i += 4) {
      float w = wld[i];
      ushort2 v = *reinterpret_cast<const ushort2*>(x + (size_t)sld[i] * 256 + ln * 2);
      a0 += bf2f(v.x) * w; a1 += bf2f(v.y) * w;
    }
  }
  if (wv) { red[wv - 1][ln * 2] = a0; red[wv - 1][ln * 2 + 1] = a1; }
  __syncthreads();
  if (wv == 0) {
    a0 += red[0][ln * 2] + red[1][ln * 2] + red[2][ln * 2];
    a1 += red[0][ln * 2 + 1] + red[1][ln * 2 + 1] + red[2][ln * 2 + 1];
    float s = -dinv0[c];
    ushort2 o; o.x = f2bf(a0 * s); o.y = f2bf(a1 * s);
    *reinterpret_cast<ushort2*>(out + (size_t)c * 256 + ln * 2) = o;
  }
}

__global__ void k_gat_agg(const unsigned short* __restrict__ h, const int* __restrict__ rowptr,
                          const int* __restrict__ csr_src, const float* __restrict__ a_s,
                          const float* __restrict__ a_d, const float* __restrict__ bias,
                          unsigned short* __restrict__ out) {
  __shared__ int sld[128];
  __shared__ float eld[128];
  __shared__ float red[3][128];
  __shared__ float sden[4];
  __shared__ float smax[256];
  int c = blockIdx.x, tid = threadIdx.x, wv = tid >> 6, ln = tid & 63;
  int r0 = rowptr[c], r1 = rowptr[c + 1];
  float adc = a_d[c];
  float es = a_s[c] + adc;
  es = es >= 0.f ? es : 0.2f * es;
  float m = es;
  for (int i = r0 + tid; i < r1; i += 256) {
    float v = a_s[csr_src[i]] + adc;
    m = fmaxf(m, v >= 0.f ? v : 0.2f * v);
  }
  smax[tid] = m;
  __syncthreads();
  for (int sft = 128; sft; sft >>= 1) {
    if (tid < sft) smax[tid] = fmaxf(smax[tid], smax[tid + sft]);
    __syncthreads();
  }
  m = smax[0];
  float a0 = 0.f, a1 = 0.f, den = 0.f;
  for (int base = r0; base < r1; base += 128) {
    int nb = min(128, r1 - base);
    __syncthreads();
    if (tid < nb) {
      int s = csr_src[base + tid];
      sld[tid] = s;
      float v = a_s[s] + adc;
      v = v >= 0.f ? v : 0.2f * v;
      eld[tid] = expf(v - m);
    }
    __syncthreads();
    for (int i = wv; i < nb; i += 4) {
      float w = eld[i];
      den += w;
      ushort2 v = *reinterpret_cast<const ushort2*>(h + (size_t)sld[i] * 128 + ln * 2);
      a0 += w * bf2f(v.x); a1 += w * bf2f(v.y);
    }
  }
  if (wv) {
    red[wv - 1][ln * 2] = a0; red[wv - 1][ln * 2 + 1] = a1;
    if (ln == 0) sden[wv] = den;
  }
  __syncthreads();
  if (wv == 0) {
    a0 += red[0][ln * 2] + red[1][ln * 2] + red[2][ln * 2];
    a1 += red[0][ln * 2 + 1] + red[1][ln * 2 + 1] + red[2][ln * 2 + 1];
    den += sden[1] + sden[2] + sden[3];
    float ws = expf(es - m);
    den += ws;
    ushort2 xc = *reinterpret_cast<const ushort2*>(h + (size_t)c * 128 + ln * 2);
    a0 += ws * bf2f(xc.x); a1 += ws * bf2f(xc.y);
    float inv = 1.f / den;
    float v0 = a0 * inv + bias[ln * 2];
    float v1 = a1 * inv + bias[ln * 2 + 1];
    v0 = v0 > 0.f ? v0 : expm1f(v0);
    v1 = v1 > 0.f ? v1 : expm1f(v1);
    ushort2 o; o.x = f2bf(v0); o.y = f2bf(v1);
    *reinterpret_cast<ushort2*>(out + (size_t)c * 128 + ln * 2) = o;
  }
}

// ---------------- batch norm (partials, no atomics) ----------------
__global__ void k_bn_stats(const float* __restrict__ x, float* __restrict__ psum,
                           float* __restrict__ psq, int F) {
  int tid = threadIdx.x;
  int f = tid & (F - 1);
  int rstep = 256 / F;
  int r0 = tid / F;
  int base = blockIdx.x * 64;  // grid 64
  float s = 0.f, s2 = 0.f;
  for (int rr = r0; rr < 64; rr += rstep) {
    float v = x[(size_t)(base + rr) * F + f];
    s += v;
    s2 += v * v;
  }
  int slot = blockIdx.x * rstep + r0;
  psum[(size_t)slot * F + f] = s;
  psq[(size_t)slot * F + f] = s2;
}

// bn2: fused final+apply. grid 256 x 256 thr; F=128; each block: 16 rows.
__global__ void k_bn_apply2(const float* __restrict__ x, const float* __restrict__ psum,
                            const float* __restrict__ psq, const float* __restrict__ g,
                            const float* __restrict__ be, unsigned short* __restrict__ y,
                            int ldY) {
  __shared__ float sc[128], sh[128];
  int tid = threadIdx.x;
  if (tid < 128) {
    float s = 0.f, s2 = 0.f;
    for (int i = 0; i < 128; i++) {  // S = 16384/128
      s += psum[(size_t)i * 128 + tid];
      s2 += psq[(size_t)i * 128 + tid];
    }
    float invM = 1.f / (float)NN;
    float mu = s * invM;
    float var = s2 * invM - mu * mu;
    float scv = g[tid] * rsqrtf(var + 1e-5f);
    sc[tid] = scv;
    sh[tid] = be[tid] - mu * scv;
  }
  __syncthreads();
  int f = tid & 127, rhalf = tid >> 7;
  int row0 = blockIdx.x * 16;
  for (int rr = 0; rr < 8; rr++) {
    int row = row0 + rr * 2 + rhalf;
    float v = fmaxf(x[(size_t)row * 128 + f] * sc[f] + sh[f], 0.f);
    y[(size_t)row * ldY + f] = f2bf(v);
  }
}

// ---------------- launch ----------------
static inline int cdiv(int a, int b) { return (a + b - 1) / b; }

extern "C" void kernel_launch(void* const* d_in, const int* in_sizes, int n_in,
                              void* d_out, int out_size, void* d_ws, size_t ws_size,
                              hipStream_t stream) {
  const int* ei = (const int*)d_in[0];
  const int* ei0 = ei;
  const int* ei1 = ei + NE;
  const int* node_x = (const int*)d_in[1];
  const float* user_w = (const float*)d_in[2];
  const float* item_w = (const float*)d_in[3];
  const float* mlp_w1 = (const float*)d_in[4];
  const float* mlp_b1 = (const float*)d_in[5];
  const float* mlp_w2 = (const float*)d_in[6];
  const float* mlp_b2 = (const float*)d_in[7];
  const float* gcn_w1 = (const float*)d_in[8];
  // d_in[9] gcn_b1 / d_in[13] gcn_b2: cancelled by batch_norm mean subtraction
  const float* bn1_g = (const float*)d_in[10];
  const float* bn1_b = (const float*)d_in[11];
  const float* gcn_w2 = (const float*)d_in[12];
  const float* bn2_g = (const float*)d_in[14];
  const float* bn2_b = (const float*)d_in[15];
  const float* sage_wl = (const float*)d_in[16];
  const float* sage_bl = (const float*)d_in[17];
  const float* sage_wr = (const float*)d_in[18];
  const float* cheb_w0 = (const float*)d_in[19];
  const float* cheb_w1 = (const float*)d_in[20];
  const float* cheb_b = (const float*)d_in[21];
  const float* gat1_w = (const float*)d_in[22];
  const float* gat1_as = (const float*)d_in[23];
  const float* gat1_ad = (const float*)d_in[24];
  const float* gat1_b = (const float*)d_in[25];
  const float* gat2_w = (const float*)d_in[26];
  const float* gat2_as = (const float*)d_in[27];
  const float* gat2_ad = (const float*)d_in[28];
  const float* gat2_b = (const float*)d_in[29];
  const float* pred_w = (const float*)d_in[30];
  const float* pred_b = (const float*)d_in[31];

  // ---- workspace layout ----
  char* w = (char*)d_ws;
  size_t off = 0;
  auto alloc = [&](size_t bytes) -> char* {
    char* p = w + off;
    off = (off + bytes + 255) & ~(size_t)255;
    return p;
  };
  unsigned short* x0b = (unsigned short*)alloc((size_t)NN * 128 * 2);
  unsigned short* x1b = (unsigned short*)alloc((size_t)NN * 1024 * 2);
  unsigned short* x2b = (unsigned short*)alloc((size_t)NN * 512 * 2);
  unsigned short* h1b = (unsigned short*)alloc((size_t)NN * 256 * 2);
  unsigned short* catS = (unsigned short*)alloc((size_t)NN * 256 * 2);  // [sage_agg | xb]
  unsigned short* catC = (unsigned short*)alloc((size_t)NN * 256 * 2);  // [xa | cheb_agg]
  unsigned short* xb2 = (unsigned short*)alloc((size_t)NN * 128 * 2);
  unsigned short* hb = (unsigned short*)alloc((size_t)NN * 128 * 2);
  unsigned short* xa2 = (unsigned short*)alloc((size_t)NN * 128 * 2);
  unsigned short* xb3 = (unsigned short*)alloc((size_t)NN * 128 * 2);
  float* agg = (float*)alloc((size_t)NN * 256 * 4);
  unsigned short* w1t = (unsigned short*)alloc((size_t)1024 * 128 * 2);
  unsigned short* w2t = (unsigned short*)alloc((size_t)512 * 1024 * 2);
  unsigned short* g1t = (unsigned short*)alloc((size_t)256 * 512 * 2);
  unsigned short* g2t = (unsigned short*)alloc((size_t)128 * 256 * 2);
  unsigned short* sgt = (unsigned short*)alloc((size_t)128 * 256 * 2);  // [Wl;Wr]^T
  unsigned short* cht = (unsigned short*)alloc((size_t)128 * 256 * 2);  // [W0;W1]^T
  unsigned short* a1t = (unsigned short*)alloc((size_t)128 * 128 * 2);
  unsigned short* a2t = (unsigned short*)alloc((size_t)128 * 128 * 2);
  unsigned short* predT = (unsigned short*)alloc((size_t)NPAD * 128 * 2);
  int* deg0 = (int*)alloc(NN * 4);
  int* deg1 = (int*)alloc(NN * 4);  // contiguous after deg0
  int* rowptr = (int*)alloc((NN + 1) * 4);
  int* cursor = (int*)alloc(NN * 4);
  int* csr_src = (int*)alloc(NE * 4);
  float* dinvA = (float*)alloc(NN * 4);
  float* dinv0 = (float*)alloc(NN * 4);
  float* a_s = (float*)alloc(NN * 4);
  float* a_d = (float*)alloc(NN * 4);
  float* psum = (float*)alloc(16384 * 4);
  float* psq = (float*)alloc(16384 * 4);

  // ---- fused launch 0: weight cvt + degree count + gather ----
  CvtArgs ca;
  int t0 = 0;
  auto mkd = [&](int i, const float* src, unsigned short* dst, int K, int N, int ld, int koff,
                 int ntx) {
    ca.d[i] = {src, dst, K, N, ld, koff, t0, ntx};
    t0 += ntx * (K / 32);
  };
  mkd(0, mlp_w1, w1t, 128, 1024, 128, 0, 32);
  mkd(1, mlp_w2, w2t, 1024, 512, 1024, 0, 16);
  mkd(2, gcn_w1, g1t, 512, 256, 512, 0, 8);
  mkd(3, gcn_w2, g2t, 256, 128, 256, 0, 4);
  mkd(4, sage_wl, sgt, 128, 128, 256, 0, 4);
  mkd(5, sage_wr, sgt, 128, 128, 256, 128, 4);
  mkd(6, cheb_w0, cht, 128, 128, 256, 0, 4);
  mkd(7, cheb_w1, cht, 128, 128, 256, 128, 4);
  mkd(8, gat1_w, a1t, 128, 128, 128, 0, 4);
  mkd(9, gat2_w, a2t, 128, 128, 128, 0, 4);
  mkd(10, pred_w, predT, 128, NCLS, 128, 0, NPAD / 32);

  hipMemsetAsync(deg0, 0, 2 * NN * 4, stream);
  k_fused0<<<t0 + 512 + NN / 2, 256, 0, stream>>>(ca, t0, ei, deg0, deg1, node_x, user_w,
                                                  item_w, x0b);
  k_scan4096<<<1, 1024, 0, stream>>>(deg1, deg0, rowptr, cursor, dinvA, dinv0);
  k_fill<<<cdiv(NE, 256), 256, 0, stream>>>(ei0, ei1, cursor, csr_src);

  // ---- trunk ----
  k_bgemm<1><<<dim3(8, 32), 256, 0, stream>>>(x0b, w1t, mlp_b1, x1b, 1024, 128, 1);
  k_bgemm<1><<<dim3(4, 32), 256, 0, stream>>>(x1b, w2t, mlp_b2, x2b, 512, 1024, 1);

  // GCN1 (512 -> 256)
  k_bgemm_s<0><<<dim3(2, 128), 256, 0, stream>>>(x2b, g1t, nullptr, h1b, 256, 512, 0,
                                                 nullptr, nullptr, nullptr, nullptr, nullptr,
                                                 nullptr, nullptr, nullptr);
  k_gcn_agg<4><<<NN, 256, 0, stream>>>(h1b, rowptr, csr_src, dinvA, agg);
  k_bn_stats<<<64, 256, 0, stream>>>(agg, psum, psq, 256);

  // GCN2 (256 -> 128): bn1 final+affine+relu fused into A-staging
  k_bgemm_s<1><<<dim3(1, 128), 256, 0, stream>>>(agg, g2t, nullptr, hb, 128, 256, 0,
                                                 psum, psq, bn1_g, bn1_b, nullptr, nullptr,
                                                 nullptr, nullptr);
  k_gcn_agg<2><<<NN, 256, 0, stream>>>(hb, rowptr, csr_src, dinvA, agg);
  k_bn_stats<<<64, 256, 0, stream>>>(agg, psum, psq, 128);
  k_bn_apply2<<<256, 256, 0, stream>>>(agg, psum, psq, bn2_g, bn2_b, catS + 128, 256);

  // SAGE: agg into catS left; fused GEMM [agg|x] @ [Wl;Wr] + bl, relu -> catC left
  k_sage_agg<<<NN, 256, 0, stream>>>(catS + 128, rowptr, csr_src, catS);
  k_bgemm_s<0><<<dim3(1, 128), 256, 0, stream>>>(catS, sgt, sage_bl, catC, 256, 256, 1,
                                                 nullptr, nullptr, nullptr, nullptr, nullptr,
                                                 nullptr, nullptr, nullptr);

  // Cheb: agg into catC right; fused GEMM [x|tx1] @ [W0;W1] + b, relu -> xb2
  k_cheb_agg<<<NN, 256, 0, stream>>>(catC, rowptr, csr_src, dinv0, catC + 128);
  k_bgemm_s<0><<<dim3(1, 128), 256, 0, stream>>>(catC, cht, cheb_b, xb2, 128, 256, 1,
                                                 nullptr, nullptr, nullptr, nullptr, nullptr,
                                                 nullptr, nullptr, nullptr);

  // GAT1: GEMM + fused per-row dots
  k_bgemm_s<2><<<dim3(1, 128), 256, 0, stream>>>(xb2, a1t, nullptr, hb, 128, 128, 0,
                                                 nullptr, nullptr, nullptr, nullptr,
                                                 gat1_as, gat1_ad, a_s, a_d);
  k_gat_agg<<<NN, 256, 0, stream>>>(hb, rowptr, csr_src, a_s, a_d, gat1_b, xa2);

  // GAT2
  k_bgemm_s<2><<<dim3(1, 128), 256, 0, stream>>>(xa2, a2t, nullptr, hb, 128, 128, 0,
                                                 nullptr, nullptr, nullptr, nullptr,
                                                 gat2_as, gat2_ad, a_s, a_d);
  k_gat_agg<<<NN, 256, 0, stream>>>(hb, rowptr, csr_src, a_s, a_d, gat2_b, xb3);

  // ---- final prediction GEMM (B-resident, 8 M-tiles/block, global_load_lds staging) ----
  k_pred_gemm<<<dim3(NPAD / 128, 4), 256, 0, stream>>>(xb3, predT, pred_b, (float*)d_out);
}